// Round 7
// baseline (202.233 us; speedup 1.0000x reference)
//
#include <hip/hip_runtime.h>

// ---------------------------------------------------------------------------
// Attention: y = softmax( (xWq^T)(xWk^T)^T / sqrt(128) ) (xWv^T)
// B=4, N=4096, H=OUT=128. fp32 I/O, bf16 MFMA compute.
//
// R7: flash ingest floor = K/V bytes x (rows / rows-per-wave). r6 (32 rows/
// wave) = 1.05GB L2 = 30us floor. Now 64 q-rows (4 q-tiles) per wave ->
// 524MB. oacc (144 VGPR) forces the allocator past the 128-reg cliff that
// strangled r2/r4/r6. Q block-shared in LDS; S computed in 2 nt-chunks to
// cap sv regs; S=8 key splits: 4 in-block (LDS fp32 combine) x 2 across
// blocks (deterministic fp32 partials + tiny norm kernel).
// ---------------------------------------------------------------------------

typedef __bf16 bf16;
typedef __attribute__((ext_vector_type(8))) __bf16 bf16x8;
typedef __attribute__((ext_vector_type(4))) float f32x4;

#define MFMA16(a, b, c) __builtin_amdgcn_mfma_f32_16x16x32_bf16(a, b, c, 0, 0, 0)

#if __has_builtin(__builtin_amdgcn_exp2f)
#define EXP2F(x) __builtin_amdgcn_exp2f(x)
#else
#define EXP2F(x) exp2f(x)
#endif

static constexpr int BATCH = 4;
static constexpr int N = 4096;
static constexpr int D = 128;
static constexpr int ROWS = BATCH * N;  // 16384
// fold 1/sqrt(128) and log2(e) into q so softmax is raw exp2
static constexpr float QSCALE = 0.088388347648318447f * 1.4426950408889634f;

__device__ inline bf16x8 ld8_f32_bf16(const float* __restrict__ p) {
    f32x4 a = *(const f32x4*)p;
    f32x4 b = *(const f32x4*)(p + 4);
    bf16x8 r;
    r[0] = (bf16)a[0]; r[1] = (bf16)a[1]; r[2] = (bf16)a[2]; r[3] = (bf16)a[3];
    r[4] = (bf16)b[0]; r[5] = (bf16)b[1]; r[6] = (bf16)b[2]; r[7] = (bf16)b[3];
    return r;
}

// Fragment layouts (16x16x32 bf16; lane = quad*16 + l16):
//  qf/kf: (tile,row,d) -> ((tile*4 + (d>>5))*64 + ((d&31)>>3)*16 + row)*8 + (d&7)
//  vf:    (o,key)      -> ((vg*8 + (o>>4))*64 + ((key&31)>>3)*16 + (o&15))*8 + (key&7)
//         with vg = batch*128 + (key_in_batch>>5)

// ---------------------------------------------------------------------------
// proj_all (unchanged from r6): grid 256 x 256. Block = 64 tokens.
// ---------------------------------------------------------------------------
__global__ __launch_bounds__(256) void proj_all(const float* __restrict__ x,
                                                const float* __restrict__ Wq,
                                                const float* __restrict__ Wk,
                                                const float* __restrict__ Wv,
                                                bf16* __restrict__ qf,
                                                bf16* __restrict__ kf,
                                                bf16* __restrict__ vf) {
    __shared__ __attribute__((aligned(16))) bf16 Wl[D * D];
    __shared__ __attribute__((aligned(16))) bf16 Scr[4][2560];

    const int lane = threadIdx.x & 63;
    const int w = threadIdx.x >> 6;
    const int l16 = lane & 15;
    const int quad = lane >> 4;
    const int tok0 = blockIdx.x * 64 + w * 16;
    const int tile = tok0 >> 4;

    bf16x8 xa[4];
#pragma unroll
    for (int ks = 0; ks < 4; ks++)
        xa[ks] = ld8_f32_bf16(x + (tok0 + l16) * D + ks * 32 + quad * 8);

    const float* Ws[3] = {Wq, Wk, Wv};

    for (int ph = 0; ph < 3; ph++) {
        __syncthreads();
        {
            const float* __restrict__ W = Ws[ph];
            const int r = threadIdx.x >> 1;
            const int c0 = (threadIdx.x & 1) * 64;
#pragma unroll
            for (int g = 0; g < 8; g++) {
                const int h = c0 + g * 8;
                bf16x8 v = ld8_f32_bf16(W + r * D + h);
                const int frag = (r >> 4) * 4 + (h >> 5);
                const int ln = ((h & 31) >> 3) * 16 + (r & 15);
                *(bf16x8*)&Wl[(frag * 64 + ln) * 8] = v;
            }
        }
        __syncthreads();

        if (ph < 2) {
            bf16* __restrict__ outp = (ph == 0) ? qf : kf;
            const float scale = (ph == 0) ? QSCALE : 1.0f;
            bf16* __restrict__ T = Scr[w];  // [16][136]
#pragma unroll
            for (int nt = 0; nt < 8; nt++) {
                f32x4 acc = {0.f, 0.f, 0.f, 0.f};
#pragma unroll
                for (int ks = 0; ks < 4; ks++) {
                    bf16x8 bw = *(const bf16x8*)&Wl[((nt * 4 + ks) * 64 + lane) * 8];
                    acc = MFMA16(xa[ks], bw, acc);
                }
#pragma unroll
                for (int rg = 0; rg < 4; rg++)
                    T[(quad * 4 + rg) * 136 + nt * 16 + l16] = (bf16)(acc[rg] * scale);
            }
#pragma unroll
            for (int ks = 0; ks < 4; ks++) {
                bf16x8 frag = *(const bf16x8*)&T[l16 * 136 + ks * 32 + quad * 8];
                *(bf16x8*)(outp + (((size_t)tile * 4 + ks) * 64 + lane) * 8) = frag;
            }
        } else {
            bf16* __restrict__ T = Scr[w];  // [128][20]
#pragma unroll
            for (int mt = 0; mt < 8; mt++) {
                f32x4 acc = {0.f, 0.f, 0.f, 0.f};
#pragma unroll
                for (int ks = 0; ks < 4; ks++) {
                    bf16x8 aw = *(const bf16x8*)&Wl[((mt * 4 + ks) * 64 + lane) * 8];
                    acc = MFMA16(aw, xa[ks], acc);
                }
#pragma unroll
                for (int rg = 0; rg < 4; rg++)
                    T[(mt * 16 + quad * 4 + rg) * 20 + l16] = (bf16)acc[rg];
            }
            const int batch = tok0 >> 12;
            const int tokb = tok0 & (N - 1);
            const size_t vg = batch * 128 + (tokb >> 5);
            const int q0v = (tokb & 31) >> 3;
            const int dq = (lane >> 4) & 1;
            const int o15 = lane & 15;
#pragma unroll
            for (int s = 0; s < 4; s++) {
                const int ot = s * 2 + (lane >> 5);
                bf16x8 frag = *(const bf16x8*)&T[(ot * 16 + o15) * 20 + dq * 8];
                *(bf16x8*)(vf + ((vg * 8 + ot) * 64 + (q0v + dq) * 16 + o15) * 8) = frag;
            }
        }
    }
}

// ---------------------------------------------------------------------------
// flash: grid 512 x 256. Block = (batch, qg, h): 64 q-rows (4 tiles, shared
// by all 4 waves via LDS Q) x key-half h. Wave w covers keys
// [(h*4+w)*512, +512) = 8 iters of 64. In-block 4-way fp32 LDS combine,
// then deterministic per-half partial to global; norm kernel finishes.
// ---------------------------------------------------------------------------
__global__ __launch_bounds__(256) __attribute__((amdgpu_waves_per_eu(2, 2)))
void flash(const bf16* __restrict__ qf,
           const bf16* __restrict__ kf,
           const bf16* __restrict__ vf,
           float* __restrict__ pbuf,
           float* __restrict__ lbuf) {
    // main: Qs 16KB @0 | Ps 4 waves x 4 qt x 16x72 bf16 = 36.9KB @16KB
    // combine (aliased): Rs[3][2][16][148] f32 = 56832B
    __shared__ __attribute__((aligned(16))) unsigned char smem[56832];

    const int lane = threadIdx.x & 63;
    const int w = threadIdx.x >> 6;  // key-split within half
    const int l16 = lane & 15;
    const int quad = lane >> 4;

    const int batch = (blockIdx.x & 7) >> 1;  // XCD-pinned: 2 XCDs per batch
    const int h = blockIdx.x & 1;             // key half
    const int qg = blockIdx.x >> 3;           // 0..63 q-group within batch
    const int qt0 = (batch * 64 + qg) * 4;    // global q-tile base
    const int q0 = qt0 * 16;

    // ---- stage Q (16KB, contiguous in fragment layout) into LDS ----
    bf16* __restrict__ Qs = (bf16*)smem;
    {
        const bf16x8* __restrict__ src = (const bf16x8*)qf + (size_t)qt0 * 256;
        bf16x8* __restrict__ dst = (bf16x8*)Qs;
#pragma unroll
        for (int i = 0; i < 4; i++)
            dst[threadIdx.x + i * 256] = src[threadIdx.x + i * 256];
    }
    __syncthreads();

    bf16* __restrict__ Psw = (bf16*)smem + 8192 + w * 4608;  // [4 qt][16][72]

    f32x4 oacc[4][9];
#pragma unroll
    for (int qt = 0; qt < 4; qt++)
#pragma unroll
        for (int i = 0; i < 9; i++) oacc[qt][i] = (f32x4){0.f, 0.f, 0.f, 0.f};

    bf16x8 vone;
#pragma unroll
    for (int j = 0; j < 8; j++) vone[j] = (bf16)1.0f;

    const int kbb0 = (h * 4 + w) * 512;  // key base within batch

#pragma unroll 1
    for (int it = 0; it < 8; it++) {
        const int kbb = kbb0 + it * 64;
        const int kt = batch * 256 + (kbb >> 4);

        // ---- S in 2 nt-chunks (sv capped at 32 regs) ----
#pragma unroll
        for (int ntc = 0; ntc < 2; ntc++) {
            f32x4 sv[4][2];
#pragma unroll
            for (int qt = 0; qt < 4; qt++)
#pragma unroll
                for (int nt = 0; nt < 2; nt++) sv[qt][nt] = (f32x4){0.f, 0.f, 0.f, 0.f};
#pragma unroll
            for (int ks = 0; ks < 4; ks++) {
                bf16x8 aqk[4];
#pragma unroll
                for (int qt = 0; qt < 4; qt++)
                    aqk[qt] = *(const bf16x8*)&Qs[((qt * 4 + ks) * 64 + lane) * 8];
                bf16x8 bkk[2];
#pragma unroll
                for (int nt = 0; nt < 2; nt++)
                    bkk[nt] = *(const bf16x8*)(kf +
                        (((size_t)(kt + ntc * 2 + nt) * 4 + ks) * 64 + lane) * 8);
#pragma unroll
                for (int nt = 0; nt < 2; nt++)
#pragma unroll
                    for (int qt = 0; qt < 4; qt++)
                        sv[qt][nt] = MFMA16(aqk[qt], bkk[nt], sv[qt][nt]);
            }
            // P = exp2(S) -> wave-private LDS strips
#pragma unroll
            for (int qt = 0; qt < 4; qt++)
#pragma unroll
                for (int nt = 0; nt < 2; nt++)
#pragma unroll
                    for (int rg = 0; rg < 4; rg++)
                        Psw[qt * 1152 + (quad * 4 + rg) * 72 + (ntc * 2 + nt) * 16 + l16] =
                            (bf16)EXP2F(sv[qt][nt][rg]);
        }

        // ---- P back as A-fragments ----
        bf16x8 ap[4][2];
#pragma unroll
        for (int qt = 0; qt < 4; qt++)
#pragma unroll
            for (int ks2 = 0; ks2 < 2; ks2++)
                ap[qt][ks2] =
                    *(const bf16x8*)&Psw[qt * 1152 + l16 * 72 + ks2 * 32 + quad * 8];

        // ---- O += P.V (V fragments shared by all 4 q-tiles) ----
        const size_t vg = batch * 128 + (kbb >> 5);
#pragma unroll
        for (int ot = 0; ot < 8; ot++) {
            bf16x8 bv0 = *(const bf16x8*)(vf + (((vg + 0) * 8 + ot) * 64 + lane) * 8);
            bf16x8 bv1 = *(const bf16x8*)(vf + (((vg + 1) * 8 + ot) * 64 + lane) * 8);
#pragma unroll
            for (int qt = 0; qt < 4; qt++) {
                oacc[qt][ot] = MFMA16(ap[qt][0], bv0, oacc[qt][ot]);
                oacc[qt][ot] = MFMA16(ap[qt][1], bv1, oacc[qt][ot]);
            }
        }
#pragma unroll
        for (int qt = 0; qt < 4; qt++) {
            oacc[qt][8] = MFMA16(ap[qt][0], vone, oacc[qt][8]);
            oacc[qt][8] = MFMA16(ap[qt][1], vone, oacc[qt][8]);
        }
    }

    // ---- in-block combine of the 4 splits (2 qt per round) ----
    __syncthreads();
    float* __restrict__ Rs = (float*)smem;  // [3][2][16][148]
#pragma unroll 1
    for (int chunk = 0; chunk < 2; chunk++) {
        if (chunk) __syncthreads();
        if (w > 0) {
#pragma unroll
            for (int j = 0; j < 2; j++) {
                const int qt = chunk * 2 + j;
                float* __restrict__ dst = Rs + ((w - 1) * 2 + j) * (16 * 148);
#pragma unroll
                for (int t = 0; t < 9; t++)
#pragma unroll
                    for (int rg = 0; rg < 4; rg++)
                        dst[(quad * 4 + rg) * 148 + t * 16 + l16] = oacc[qt][t][rg];
            }
        }
        __syncthreads();
        if (w == 0) {
#pragma unroll
            for (int j = 0; j < 2; j++) {
                const int qt = chunk * 2 + j;
#pragma unroll
                for (int sIdx = 0; sIdx < 3; sIdx++) {
                    const float* __restrict__ src = Rs + (sIdx * 2 + j) * (16 * 148);
#pragma unroll
                    for (int t = 0; t < 9; t++)
#pragma unroll
                        for (int rg = 0; rg < 4; rg++)
                            oacc[qt][t][rg] += src[(quad * 4 + rg) * 148 + t * 16 + l16];
                }
            }
        }
    }

    // ---- write the per-half partial (fp32, coalesced) ----
    if (w == 0) {
#pragma unroll
        for (int qt = 0; qt < 4; qt++) {
#pragma unroll
            for (int rg = 0; rg < 4; rg++) {
                const int row = q0 + qt * 16 + quad * 4 + rg;
                float* __restrict__ prow = pbuf + ((size_t)h * ROWS + row) * D;
#pragma unroll
                for (int t = 0; t < 8; t++)
                    prow[t * 16 + l16] = oacc[qt][t][rg];
            }
            if (l16 == 0) {
#pragma unroll
                for (int rg = 0; rg < 4; rg++)
                    lbuf[h * ROWS + q0 + qt * 16 + quad * 4 + rg] = oacc[qt][8][rg];
            }
        }
    }
}

// ---------------------------------------------------------------------------
// norm: y = (P0 + P1) / (l0 + l1). grid 512 x 256; thread = 16-col segment.
// ---------------------------------------------------------------------------
__global__ __launch_bounds__(256) void norm(const float* __restrict__ pbuf,
                                            const float* __restrict__ lbuf,
                                            float* __restrict__ out) {
    const int idx = blockIdx.x * 256 + threadIdx.x;  // 0..131071
    const int row = idx >> 3;
    const int seg = (idx & 7) * 16;
    const float rl = 1.0f / (lbuf[row] + lbuf[ROWS + row]);
    const float* __restrict__ p0 = pbuf + (size_t)row * D + seg;
    const float* __restrict__ p1 = pbuf + (size_t)ROWS * D + (size_t)row * D + seg;
    float* __restrict__ o = out + (size_t)row * D + seg;
#pragma unroll
    for (int k = 0; k < 4; k++) {
        f32x4 a = *(const f32x4*)(p0 + k * 4);
        f32x4 b = *(const f32x4*)(p1 + k * 4);
        f32x4 r = {(a[0] + b[0]) * rl, (a[1] + b[1]) * rl, (a[2] + b[2]) * rl,
                   (a[3] + b[3]) * rl};
        *(f32x4*)(o + k * 4) = r;
    }
}

// ---------------------------------------------------------------------------
extern "C" void kernel_launch(void* const* d_in, const int* in_sizes, int n_in,
                              void* d_out, int out_size, void* d_ws, size_t ws_size,
                              hipStream_t stream) {
    const float* x = (const float*)d_in[0];
    const float* Wq = (const float*)d_in[1];
    const float* Wk = (const float*)d_in[2];
    const float* Wv = (const float*)d_in[3];
    float* y = (float*)d_out;

    // ws: qf 4MB | kf 4MB | vf 4MB | pbuf 16MB | lbuf 128KB
    bf16* qf = (bf16*)d_ws;
    bf16* kf = qf + (size_t)ROWS * D;
    bf16* vf = kf + (size_t)ROWS * D;
    float* pbuf = (float*)(vf + (size_t)ROWS * D);
    float* lbuf = pbuf + (size_t)2 * ROWS * D;

    proj_all<<<256, 256, 0, stream>>>(x, Wq, Wk, Wv, qf, kf, vf);
    flash<<<512, 256, 0, stream>>>(qf, kf, vf, pbuf, lbuf);
    norm<<<512, 256, 0, stream>>>(pbuf, lbuf, y);
}

// Round 8
// 181.837 us; speedup vs baseline: 1.1122x; 1.1122x over previous
//
#include <hip/hip_runtime.h>

// ---------------------------------------------------------------------------
// Attention: y = softmax( (xWq^T)(xWk^T)^T / sqrt(128) ) (xWv^T)
// B=4, N=4096, H=OUT=128. fp32 I/O, bf16 MFMA compute.
//
// R8: r7's regression was a scratch-spill bug, not a structure failure:
// the combine loop's `#pragma unroll 1` made oacc[] subscripts runtime ->
// SROA failed -> the whole 144-reg accumulator array lived in scratch
// (WRITE_SIZE 273MB of spill traffic). Fix: fully unroll the combine so
// every private-array subscript is a compile-time constant. Structure
// otherwise identical to r7: 64 q-rows/wave (524MB L2 ingest), Q in LDS,
// S=8 splits = 4 in-block (LDS fp32 combine) x 2 across blocks (fp32
// partials + norm kernel).
// ---------------------------------------------------------------------------

typedef __bf16 bf16;
typedef __attribute__((ext_vector_type(8))) __bf16 bf16x8;
typedef __attribute__((ext_vector_type(4))) float f32x4;

#define MFMA16(a, b, c) __builtin_amdgcn_mfma_f32_16x16x32_bf16(a, b, c, 0, 0, 0)

#if __has_builtin(__builtin_amdgcn_exp2f)
#define EXP2F(x) __builtin_amdgcn_exp2f(x)
#else
#define EXP2F(x) exp2f(x)
#endif

static constexpr int BATCH = 4;
static constexpr int N = 4096;
static constexpr int D = 128;
static constexpr int ROWS = BATCH * N;  // 16384
// fold 1/sqrt(128) and log2(e) into q so softmax is raw exp2
static constexpr float QSCALE = 0.088388347648318447f * 1.4426950408889634f;

__device__ inline bf16x8 ld8_f32_bf16(const float* __restrict__ p) {
    f32x4 a = *(const f32x4*)p;
    f32x4 b = *(const f32x4*)(p + 4);
    bf16x8 r;
    r[0] = (bf16)a[0]; r[1] = (bf16)a[1]; r[2] = (bf16)a[2]; r[3] = (bf16)a[3];
    r[4] = (bf16)b[0]; r[5] = (bf16)b[1]; r[6] = (bf16)b[2]; r[7] = (bf16)b[3];
    return r;
}

// Fragment layouts (16x16x32 bf16; lane = quad*16 + l16):
//  qf/kf: (tile,row,d) -> ((tile*4 + (d>>5))*64 + ((d&31)>>3)*16 + row)*8 + (d&7)
//  vf:    (o,key)      -> ((vg*8 + (o>>4))*64 + ((key&31)>>3)*16 + (o&15))*8 + (key&7)
//         with vg = batch*128 + (key_in_batch>>5)

// ---------------------------------------------------------------------------
// proj_all (unchanged from r6): grid 256 x 256. Block = 64 tokens.
// ---------------------------------------------------------------------------
__global__ __launch_bounds__(256) void proj_all(const float* __restrict__ x,
                                                const float* __restrict__ Wq,
                                                const float* __restrict__ Wk,
                                                const float* __restrict__ Wv,
                                                bf16* __restrict__ qf,
                                                bf16* __restrict__ kf,
                                                bf16* __restrict__ vf) {
    __shared__ __attribute__((aligned(16))) bf16 Wl[D * D];
    __shared__ __attribute__((aligned(16))) bf16 Scr[4][2560];

    const int lane = threadIdx.x & 63;
    const int w = threadIdx.x >> 6;
    const int l16 = lane & 15;
    const int quad = lane >> 4;
    const int tok0 = blockIdx.x * 64 + w * 16;
    const int tile = tok0 >> 4;

    bf16x8 xa[4];
#pragma unroll
    for (int ks = 0; ks < 4; ks++)
        xa[ks] = ld8_f32_bf16(x + (tok0 + l16) * D + ks * 32 + quad * 8);

    const float* Ws[3] = {Wq, Wk, Wv};

    for (int ph = 0; ph < 3; ph++) {
        __syncthreads();
        {
            const float* __restrict__ W = Ws[ph];
            const int r = threadIdx.x >> 1;
            const int c0 = (threadIdx.x & 1) * 64;
#pragma unroll
            for (int g = 0; g < 8; g++) {
                const int h = c0 + g * 8;
                bf16x8 v = ld8_f32_bf16(W + r * D + h);
                const int frag = (r >> 4) * 4 + (h >> 5);
                const int ln = ((h & 31) >> 3) * 16 + (r & 15);
                *(bf16x8*)&Wl[(frag * 64 + ln) * 8] = v;
            }
        }
        __syncthreads();

        if (ph < 2) {
            bf16* __restrict__ outp = (ph == 0) ? qf : kf;
            const float scale = (ph == 0) ? QSCALE : 1.0f;
            bf16* __restrict__ T = Scr[w];  // [16][136]
#pragma unroll
            for (int nt = 0; nt < 8; nt++) {
                f32x4 acc = {0.f, 0.f, 0.f, 0.f};
#pragma unroll
                for (int ks = 0; ks < 4; ks++) {
                    bf16x8 bw = *(const bf16x8*)&Wl[((nt * 4 + ks) * 64 + lane) * 8];
                    acc = MFMA16(xa[ks], bw, acc);
                }
#pragma unroll
                for (int rg = 0; rg < 4; rg++)
                    T[(quad * 4 + rg) * 136 + nt * 16 + l16] = (bf16)(acc[rg] * scale);
            }
#pragma unroll
            for (int ks = 0; ks < 4; ks++) {
                bf16x8 frag = *(const bf16x8*)&T[l16 * 136 + ks * 32 + quad * 8];
                *(bf16x8*)(outp + (((size_t)tile * 4 + ks) * 64 + lane) * 8) = frag;
            }
        } else {
            bf16* __restrict__ T = Scr[w];  // [128][20]
#pragma unroll
            for (int mt = 0; mt < 8; mt++) {
                f32x4 acc = {0.f, 0.f, 0.f, 0.f};
#pragma unroll
                for (int ks = 0; ks < 4; ks++) {
                    bf16x8 aw = *(const bf16x8*)&Wl[((mt * 4 + ks) * 64 + lane) * 8];
                    acc = MFMA16(aw, xa[ks], acc);
                }
#pragma unroll
                for (int rg = 0; rg < 4; rg++)
                    T[(mt * 16 + quad * 4 + rg) * 20 + l16] = (bf16)acc[rg];
            }
            const int batch = tok0 >> 12;
            const int tokb = tok0 & (N - 1);
            const size_t vg = batch * 128 + (tokb >> 5);
            const int q0v = (tokb & 31) >> 3;
            const int dq = (lane >> 4) & 1;
            const int o15 = lane & 15;
#pragma unroll
            for (int s = 0; s < 4; s++) {
                const int ot = s * 2 + (lane >> 5);
                bf16x8 frag = *(const bf16x8*)&T[(ot * 16 + o15) * 20 + dq * 8];
                *(bf16x8*)(vf + ((vg * 8 + ot) * 64 + (q0v + dq) * 16 + o15) * 8) = frag;
            }
        }
    }
}

// ---------------------------------------------------------------------------
// flash: grid 512 x 256. Block = (batch, qg, h): 64 q-rows (4 tiles, shared
// by all 4 waves via LDS Q) x key-half h. Wave w covers keys
// [(h*4+w)*512, +512) = 8 iters of 64. In-block 4-way fp32 LDS combine
// (FULLY UNROLLED — constant subscripts, no scratch demotion), then
// deterministic per-half partial to global; norm kernel finishes.
// ---------------------------------------------------------------------------
__global__ __launch_bounds__(256) __attribute__((amdgpu_waves_per_eu(2, 2)))
void flash(const bf16* __restrict__ qf,
           const bf16* __restrict__ kf,
           const bf16* __restrict__ vf,
           float* __restrict__ pbuf,
           float* __restrict__ lbuf) {
    // main: Qs 16KB @0 | Ps 4 waves x 4 qt x 16x72 bf16 = 36.9KB @16KB
    // combine (aliased): Rs[3][2][16][148] f32 = 56832B
    __shared__ __attribute__((aligned(16))) unsigned char smem[56832];

    const int lane = threadIdx.x & 63;
    const int w = threadIdx.x >> 6;  // key-split within half
    const int l16 = lane & 15;
    const int quad = lane >> 4;

    const int batch = (blockIdx.x & 7) >> 1;  // XCD-pinned: 2 XCDs per batch
    const int h = blockIdx.x & 1;             // key half
    const int qg = blockIdx.x >> 3;           // 0..63 q-group within batch
    const int qt0 = (batch * 64 + qg) * 4;    // global q-tile base
    const int q0 = qt0 * 16;

    // ---- stage Q (16KB, contiguous in fragment layout) into LDS ----
    bf16* __restrict__ Qs = (bf16*)smem;
    {
        const bf16x8* __restrict__ src = (const bf16x8*)qf + (size_t)qt0 * 256;
        bf16x8* __restrict__ dst = (bf16x8*)Qs;
#pragma unroll
        for (int i = 0; i < 4; i++)
            dst[threadIdx.x + i * 256] = src[threadIdx.x + i * 256];
    }
    __syncthreads();

    bf16* __restrict__ Psw = (bf16*)smem + 8192 + w * 4608;  // [4 qt][16][72]

    f32x4 oacc[4][9];
#pragma unroll
    for (int qt = 0; qt < 4; qt++)
#pragma unroll
        for (int i = 0; i < 9; i++) oacc[qt][i] = (f32x4){0.f, 0.f, 0.f, 0.f};

    bf16x8 vone;
#pragma unroll
    for (int j = 0; j < 8; j++) vone[j] = (bf16)1.0f;

    const int kbb0 = (h * 4 + w) * 512;  // key base within batch

#pragma unroll 1
    for (int it = 0; it < 8; it++) {
        const int kbb = kbb0 + it * 64;
        const int kt = batch * 256 + (kbb >> 4);

        // ---- S in 2 nt-chunks (sv capped at 32 regs) ----
#pragma unroll
        for (int ntc = 0; ntc < 2; ntc++) {
            f32x4 sv[4][2];
#pragma unroll
            for (int qt = 0; qt < 4; qt++)
#pragma unroll
                for (int nt = 0; nt < 2; nt++) sv[qt][nt] = (f32x4){0.f, 0.f, 0.f, 0.f};
#pragma unroll
            for (int ks = 0; ks < 4; ks++) {
                bf16x8 aqk[4];
#pragma unroll
                for (int qt = 0; qt < 4; qt++)
                    aqk[qt] = *(const bf16x8*)&Qs[((qt * 4 + ks) * 64 + lane) * 8];
                bf16x8 bkk[2];
#pragma unroll
                for (int nt = 0; nt < 2; nt++)
                    bkk[nt] = *(const bf16x8*)(kf +
                        (((size_t)(kt + ntc * 2 + nt) * 4 + ks) * 64 + lane) * 8);
#pragma unroll
                for (int nt = 0; nt < 2; nt++)
#pragma unroll
                    for (int qt = 0; qt < 4; qt++)
                        sv[qt][nt] = MFMA16(aqk[qt], bkk[nt], sv[qt][nt]);
            }
            // P = exp2(S) -> wave-private LDS strips
#pragma unroll
            for (int qt = 0; qt < 4; qt++)
#pragma unroll
                for (int nt = 0; nt < 2; nt++)
#pragma unroll
                    for (int rg = 0; rg < 4; rg++)
                        Psw[qt * 1152 + (quad * 4 + rg) * 72 + (ntc * 2 + nt) * 16 + l16] =
                            (bf16)EXP2F(sv[qt][nt][rg]);
        }

        // ---- P back as A-fragments ----
        bf16x8 ap[4][2];
#pragma unroll
        for (int qt = 0; qt < 4; qt++)
#pragma unroll
            for (int ks2 = 0; ks2 < 2; ks2++)
                ap[qt][ks2] =
                    *(const bf16x8*)&Psw[qt * 1152 + l16 * 72 + ks2 * 32 + quad * 8];

        // ---- O += P.V (V fragments shared by all 4 q-tiles) ----
        const size_t vg = batch * 128 + (kbb >> 5);
#pragma unroll
        for (int ot = 0; ot < 8; ot++) {
            bf16x8 bv0 = *(const bf16x8*)(vf + (((vg + 0) * 8 + ot) * 64 + lane) * 8);
            bf16x8 bv1 = *(const bf16x8*)(vf + (((vg + 1) * 8 + ot) * 64 + lane) * 8);
#pragma unroll
            for (int qt = 0; qt < 4; qt++) {
                oacc[qt][ot] = MFMA16(ap[qt][0], bv0, oacc[qt][ot]);
                oacc[qt][ot] = MFMA16(ap[qt][1], bv1, oacc[qt][ot]);
            }
        }
#pragma unroll
        for (int qt = 0; qt < 4; qt++) {
            oacc[qt][8] = MFMA16(ap[qt][0], vone, oacc[qt][8]);
            oacc[qt][8] = MFMA16(ap[qt][1], vone, oacc[qt][8]);
        }
    }

    // ---- in-block combine of the 4 splits, FULLY UNROLLED (2 qt/round;
    //      all oacc subscripts compile-time constants) ----
    __syncthreads();
    float* __restrict__ Rs = (float*)smem;  // [3][2][16][148]
#pragma unroll
    for (int chunk = 0; chunk < 2; chunk++) {
        if (chunk) __syncthreads();
        if (w > 0) {
#pragma unroll
            for (int j = 0; j < 2; j++) {
                const int qt = chunk * 2 + j;
                float* __restrict__ dst = Rs + ((w - 1) * 2 + j) * (16 * 148);
#pragma unroll
                for (int t = 0; t < 9; t++)
#pragma unroll
                    for (int rg = 0; rg < 4; rg++)
                        dst[(quad * 4 + rg) * 148 + t * 16 + l16] = oacc[qt][t][rg];
            }
        }
        __syncthreads();
        if (w == 0) {
#pragma unroll
            for (int j = 0; j < 2; j++) {
                const int qt = chunk * 2 + j;
#pragma unroll
                for (int sIdx = 0; sIdx < 3; sIdx++) {
                    const float* __restrict__ src = Rs + (sIdx * 2 + j) * (16 * 148);
#pragma unroll
                    for (int t = 0; t < 9; t++)
#pragma unroll
                        for (int rg = 0; rg < 4; rg++)
                            oacc[qt][t][rg] += src[(quad * 4 + rg) * 148 + t * 16 + l16];
                }
            }
        }
    }

    // ---- write the per-half partial (fp32, coalesced) ----
    if (w == 0) {
#pragma unroll
        for (int qt = 0; qt < 4; qt++) {
#pragma unroll
            for (int rg = 0; rg < 4; rg++) {
                const int row = q0 + qt * 16 + quad * 4 + rg;
                float* __restrict__ prow = pbuf + ((size_t)h * ROWS + row) * D;
#pragma unroll
                for (int t = 0; t < 8; t++)
                    prow[t * 16 + l16] = oacc[qt][t][rg];
            }
            if (l16 == 0) {
#pragma unroll
                for (int rg = 0; rg < 4; rg++)
                    lbuf[h * ROWS + q0 + qt * 16 + quad * 4 + rg] = oacc[qt][8][rg];
            }
        }
    }
}

// ---------------------------------------------------------------------------
// norm: y = (P0 + P1) / (l0 + l1). grid 512 x 256; thread = 16-col segment.
// ---------------------------------------------------------------------------
__global__ __launch_bounds__(256) void norm(const float* __restrict__ pbuf,
                                            const float* __restrict__ lbuf,
                                            float* __restrict__ out) {
    const int idx = blockIdx.x * 256 + threadIdx.x;  // 0..131071
    const int row = idx >> 3;
    const int seg = (idx & 7) * 16;
    const float rl = 1.0f / (lbuf[row] + lbuf[ROWS + row]);
    const float* __restrict__ p0 = pbuf + (size_t)row * D + seg;
    const float* __restrict__ p1 = pbuf + (size_t)ROWS * D + (size_t)row * D + seg;
    float* __restrict__ o = out + (size_t)row * D + seg;
#pragma unroll
    for (int k = 0; k < 4; k++) {
        f32x4 a = *(const f32x4*)(p0 + k * 4);
        f32x4 b = *(const f32x4*)(p1 + k * 4);
        f32x4 r = {(a[0] + b[0]) * rl, (a[1] + b[1]) * rl, (a[2] + b[2]) * rl,
                   (a[3] + b[3]) * rl};
        *(f32x4*)(o + k * 4) = r;
    }
}

// ---------------------------------------------------------------------------
extern "C" void kernel_launch(void* const* d_in, const int* in_sizes, int n_in,
                              void* d_out, int out_size, void* d_ws, size_t ws_size,
                              hipStream_t stream) {
    const float* x = (const float*)d_in[0];
    const float* Wq = (const float*)d_in[1];
    const float* Wk = (const float*)d_in[2];
    const float* Wv = (const float*)d_in[3];
    float* y = (float*)d_out;

    // ws: qf 4MB | kf 4MB | vf 4MB | pbuf 16MB | lbuf 128KB
    bf16* qf = (bf16*)d_ws;
    bf16* kf = qf + (size_t)ROWS * D;
    bf16* vf = kf + (size_t)ROWS * D;
    float* pbuf = (float*)(vf + (size_t)ROWS * D);
    float* lbuf = pbuf + (size_t)2 * ROWS * D;

    proj_all<<<256, 256, 0, stream>>>(x, Wq, Wk, Wv, qf, kf, vf);
    flash<<<512, 256, 0, stream>>>(qf, kf, vf, pbuf, lbuf);
    norm<<<512, 256, 0, stream>>>(pbuf, lbuf, y);
}